// Round 9
// baseline (346.327 us; speedup 1.0000x reference)
//
#include <hip/hip_runtime.h>
#include <hip/hip_fp16.h>

// ---------------- preprocessing: histogram+rank, 3-phase scan (+dinv), passed scatter ----

// rank[e] = arrival order of edge e at its dst; count[d] = degree of d
__global__ void hist_rank_kernel(const int* __restrict__ dst, int E, int* __restrict__ count,
                                 int* __restrict__ rank) {
    int stride = gridDim.x * blockDim.x;
    int t = blockIdx.x * blockDim.x + threadIdx.x;
    int E4 = E >> 2;
    for (int e = t; e < E4; e += stride) {
        int4 d = ((const int4*)dst)[e];
        int4 r;
        r.x = atomicAdd(&count[d.x], 1);
        r.y = atomicAdd(&count[d.y], 1);
        r.z = atomicAdd(&count[d.z], 1);
        r.w = atomicAdd(&count[d.w], 1);
        ((int4*)rank)[e] = r;
    }
    for (int e = (E4 << 2) + t; e < E; e += stride) rank[e] = atomicAdd(&count[dst[e]], 1);
}

// phase 1: per-block (1024 counts) partial sums
__global__ void scan_partial_kernel(const int* __restrict__ count, int* __restrict__ partials,
                                    int N) {
    __shared__ int red[4];
    int t = threadIdx.x;
    int idx = blockIdx.x * 1024 + t * 4;
    int s = 0;
    if (idx + 3 < N) {
        int4 c = *(const int4*)(count + idx);
        s = c.x + c.y + c.z + c.w;
    } else {
#pragma unroll
        for (int k = 0; k < 4; ++k)
            if (idx + k < N) s += count[idx + k];
    }
#pragma unroll
    for (int off = 1; off < 64; off <<= 1) s += __shfl_xor(s, off);
    if ((t & 63) == 0) red[t >> 6] = s;
    __syncthreads();
    if (t == 0) partials[blockIdx.x] = red[0] + red[1] + red[2] + red[3];
}

// phase 2: exclusive scan of the (<=128) partials; also writes row_ptr[N] = total
__global__ void scan_top_kernel(int* __restrict__ partials, int nb, int* __restrict__ row_ptr,
                                int N) {
    __shared__ int buf[2][128];
    int t = threadIdx.x;
    buf[0][t] = (t < nb) ? partials[t] : 0;
    __syncthreads();
    int pi = 0;
    for (int off = 1; off < 128; off <<= 1) {
        int v = buf[pi][t];
        if (t >= off) v += buf[pi][t - off];
        buf[pi ^ 1][t] = v;
        pi ^= 1;
        __syncthreads();
    }
    if (t < nb) partials[t] = (t == 0) ? 0 : buf[pi][t - 1];
    if (t == 0) row_ptr[N] = buf[pi][127];
}

// phase 3: in-block exclusive scan + block offset -> row_ptr; dinv fused
__global__ void scan_apply_kernel(const int* __restrict__ count, const int* __restrict__ partials,
                                  int* __restrict__ row_ptr, float* __restrict__ dinv, int N) {
    __shared__ int wsum[4];
    int t = threadIdx.x;
    int idx = blockIdx.x * 1024 + t * 4;
    int4 c = make_int4(0, 0, 0, 0);
    if (idx + 3 < N) {
        c = *(const int4*)(count + idx);
    } else {
        if (idx + 0 < N) c.x = count[idx + 0];
        if (idx + 1 < N) c.y = count[idx + 1];
        if (idx + 2 < N) c.z = count[idx + 2];
    }
    int s = c.x + c.y + c.z + c.w;
    int incl = s;
#pragma unroll
    for (int off = 1; off < 64; off <<= 1) {
        int v = __shfl_up(incl, off);
        if ((t & 63) >= off) incl += v;
    }
    int wexcl = incl - s;
    int w = t >> 6;
    if ((t & 63) == 63) wsum[w] = incl;
    __syncthreads();
    int base = partials[blockIdx.x] + wexcl;
    for (int k = 0; k < w; ++k) base += wsum[k];
    if (idx + 0 < N) { row_ptr[idx + 0] = base;                   dinv[idx + 0] = rsqrtf((float)c.x + 1.f); }
    if (idx + 1 < N) { row_ptr[idx + 1] = base + c.x;             dinv[idx + 1] = rsqrtf((float)c.y + 1.f); }
    if (idx + 2 < N) { row_ptr[idx + 2] = base + c.x + c.y;       dinv[idx + 2] = rsqrtf((float)c.z + 1.f); }
    if (idx + 3 < N) { row_ptr[idx + 3] = base + c.x + c.y + c.z; dinv[idx + 3] = rsqrtf((float)c.w + 1.f); }
}

// atomic-free scatter with dst-range write blocking (pass p writes only a ~N/NPASS window)
#define NPASS 8
__global__ void scatter_kernel(const int* __restrict__ src, const int* __restrict__ dst,
                               const int* __restrict__ rank, int E,
                               const int* __restrict__ row_ptr, int* __restrict__ col, int N) {
    int chunk = (N + NPASS - 1) / NPASS;
    int stride = gridDim.x * blockDim.x;
    int t = blockIdx.x * blockDim.x + threadIdx.x;
    int E4 = E >> 2;
    for (int pass = 0; pass < NPASS; ++pass) {
        int lo = pass * chunk, hi = min(lo + chunk, N);
        for (int e = t; e < E4; e += stride) {
            int4 d = ((const int4*)dst)[e];
            int4 s = ((const int4*)src)[e];
            int4 r = ((const int4*)rank)[e];
            if (d.x >= lo && d.x < hi) col[row_ptr[d.x] + r.x] = s.x;
            if (d.y >= lo && d.y < hi) col[row_ptr[d.y] + r.y] = s.y;
            if (d.z >= lo && d.z < hi) col[row_ptr[d.z] + r.z] = s.z;
            if (d.w >= lo && d.w < hi) col[row_ptr[d.w] + r.w] = s.w;
        }
        for (int e = (E4 << 2) + t; e < E; e += stride) {
            int d = dst[e];
            if (d >= lo && d < hi) col[row_ptr[d] + rank[e]] = src[e];
        }
    }
}

// -------- fp32 GEMM, PRE-SCALED fp16 output: Out[r] = dinv[r] * (A @ W)[r] --------------

__global__ __launch_bounds__(256, 2) void gemm_kernel(const float* __restrict__ A,
                                                      const float* __restrict__ W,
                                                      const float* __restrict__ dinv,
                                                      __half* __restrict__ Out, int M) {
    const int K = 128;
    __shared__ float Ws[K][64];
    __shared__ float As[64][68];
    int t = threadIdx.x;
    for (int i = t * 4; i < K * 64; i += 1024)
        *(float4*)&Ws[i >> 6][i & 63] = *(const float4*)(W + i);

    int row0 = blockIdx.x * 64;
    int rt = (t >> 4) * 4;
    int ct = (t & 15) * 4;
    float acc[4][4];
#pragma unroll
    for (int m = 0; m < 4; m++) { acc[m][0] = 0.f; acc[m][1] = 0.f; acc[m][2] = 0.f; acc[m][3] = 0.f; }

    for (int k0 = 0; k0 < K; k0 += 64) {
        __syncthreads();
        for (int i = t * 4; i < 64 * 64; i += 1024) {
            int r = i >> 6, c = i & 63;
            int gr = row0 + r;
            float4 v = make_float4(0.f, 0.f, 0.f, 0.f);
            if (gr < M) v = *(const float4*)(A + (size_t)gr * K + k0 + c);
            *(float4*)&As[r][c] = v;
        }
        __syncthreads();
#pragma unroll
        for (int kk = 0; kk < 64; ++kk) {
            float a0 = As[rt + 0][kk], a1 = As[rt + 1][kk];
            float a2 = As[rt + 2][kk], a3 = As[rt + 3][kk];
            float4 w = *(float4*)&Ws[k0 + kk][ct];
            acc[0][0] += a0 * w.x; acc[0][1] += a0 * w.y; acc[0][2] += a0 * w.z; acc[0][3] += a0 * w.w;
            acc[1][0] += a1 * w.x; acc[1][1] += a1 * w.y; acc[1][2] += a1 * w.z; acc[1][3] += a1 * w.w;
            acc[2][0] += a2 * w.x; acc[2][1] += a2 * w.y; acc[2][2] += a2 * w.z; acc[2][3] += a2 * w.w;
            acc[3][0] += a3 * w.x; acc[3][1] += a3 * w.y; acc[3][2] += a3 * w.z; acc[3][3] += a3 * w.w;
        }
    }
#pragma unroll
    for (int m = 0; m < 4; m++) {
        int gr = row0 + rt + m;
        if (gr < M) {
            float dv = dinv[gr];
            union { uint2 u; __half h[4]; } pk;
            pk.h[0] = __float2half(dv * acc[m][0]);
            pk.h[1] = __float2half(dv * acc[m][1]);
            pk.h[2] = __float2half(dv * acc[m][2]);
            pk.h[3] = __float2half(dv * acc[m][3]);
            *(uint2*)(Out + (size_t)gr * 64 + ct) = pk.u;
        }
    }
}

// -------- edge aggregation core (pre-scaled fp16 payload) -------------------------------
// ONE predicated round of 32 edges in flight (8 slots x 4 groups) covers deg<=32
// (99.97% of Poisson(16) nodes); unpredicated 32-rounds only for deg>32.
// slot (g,k): edge ie = e + g + 4k.  lane l covers channels 4(l&15)..+3.

__device__ __forceinline__ float4 agg_node_h(const __half* __restrict__ Hin,
                                             const int* __restrict__ row_ptr,
                                             const int* __restrict__ col,
                                             float di, int i, int lane) {
    int g = lane >> 4;
    int l = lane & 15;
    int beg = row_ptr[i], end = row_ptr[i + 1];
    float4 acc = make_float4(0.f, 0.f, 0.f, 0.f);
    if (g == 0) {  // self-loop: di*h_i == h'_i (unscaled here; final *di below)
        union { uint2 u; __half h[4]; } v;
        v.u = *(const uint2*)(Hin + (size_t)i * 64 + l * 4);
        acc.x = __half2float(v.h[0]); acc.y = __half2float(v.h[1]);
        acc.z = __half2float(v.h[2]); acc.w = __half2float(v.h[3]);
    }
    int deg = end - beg;
    int e = beg;
    int efull = beg + ((deg >> 5) << 5);
    for (; e < efull; e += 32) {  // rare (deg>32): full unpredicated rounds
        int s[8];
#pragma unroll
        for (int k = 0; k < 8; ++k) s[k] = col[e + g + 4 * k];
        uint2 vv[8];
#pragma unroll
        for (int k = 0; k < 8; ++k) vv[k] = *(const uint2*)(Hin + (size_t)s[k] * 64 + l * 4);
#pragma unroll
        for (int k = 0; k < 8; ++k) {
            union { uint2 u; __half h[4]; } v;
            v.u = vv[k];
            acc.x += __half2float(v.h[0]); acc.y += __half2float(v.h[1]);
            acc.z += __half2float(v.h[2]); acc.w += __half2float(v.h[3]);
        }
    }
    if (e < end) {  // common case: single predicated round (up to 31 edges)
        float w[8];
        uint2 vv[8];
#pragma unroll
        for (int k = 0; k < 8; ++k) {
            int ie = e + g + 4 * k;
            int s = (ie < end) ? col[ie] : 0;   // row 0 is L1-hot everywhere
            w[k] = (ie < end) ? 1.f : 0.f;
            vv[k] = *(const uint2*)(Hin + (size_t)s * 64 + l * 4);
        }
#pragma unroll
        for (int k = 0; k < 8; ++k) {
            union { uint2 u; __half h[4]; } v;
            v.u = vv[k];
            acc.x = fmaf(w[k], __half2float(v.h[0]), acc.x);
            acc.y = fmaf(w[k], __half2float(v.h[1]), acc.y);
            acc.z = fmaf(w[k], __half2float(v.h[2]), acc.z);
            acc.w = fmaf(w[k], __half2float(v.h[3]), acc.w);
        }
    }
    acc.x += __shfl_xor(acc.x, 16); acc.y += __shfl_xor(acc.y, 16);
    acc.z += __shfl_xor(acc.z, 16); acc.w += __shfl_xor(acc.w, 16);
    acc.x += __shfl_xor(acc.x, 32); acc.y += __shfl_xor(acc.y, 32);
    acc.z += __shfl_xor(acc.z, 32); acc.w += __shfl_xor(acc.w, 32);
    acc.x *= di; acc.y *= di; acc.z *= di; acc.w *= di;
    return acc;
}

// layer 1: t = relu(agg + b0); store pre-scaled h' = dinv_i * t   (fp16)
__global__ __launch_bounds__(256, 4) void agg_relu_kernel(
        const __half* __restrict__ Hin, const int* __restrict__ row_ptr,
        const int* __restrict__ col, const float* __restrict__ dinv,
        const float* __restrict__ bias, __half* __restrict__ Hout, int N) {
    int wid = (blockIdx.x * blockDim.x + threadIdx.x) >> 6;
    if (wid >= N) return;
    int lane = threadIdx.x & 63;
    float di = dinv[wid];
    float4 r = agg_node_h(Hin, row_ptr, col, di, wid, lane);
    if (lane < 16) {
        float4 b = *(const float4*)(bias + lane * 4);
        union { uint2 u; __half h[4]; } pk;
        pk.h[0] = __float2half(di * fmaxf(r.x + b.x, 0.f));
        pk.h[1] = __float2half(di * fmaxf(r.y + b.y, 0.f));
        pk.h[2] = __float2half(di * fmaxf(r.z + b.z, 0.f));
        pk.h[3] = __float2half(di * fmaxf(r.w + b.w, 0.f));
        *(uint2*)(Hout + (size_t)wid * 64 + lane * 4) = pk.u;
    }
}

// layer 2 FUSED: g = agg(h); out = [ g@Wm + bm | g@Wl + bl ]  (agg(h@W) == agg(h)@W)
__global__ __launch_bounds__(256, 4) void agg_out_fused_kernel(
        const __half* __restrict__ Hin, const int* __restrict__ row_ptr,
        const int* __restrict__ col, const float* __restrict__ dinv,
        const float* __restrict__ Wm, const float* __restrict__ Wl,
        const float* __restrict__ bm, const float* __restrict__ bl,
        float* __restrict__ out, int N) {
    __shared__ float Ws[64][64];
    int t = threadIdx.x;
    for (int i = t * 4; i < 64 * 32; i += 1024) {
        int k = i >> 5, c = i & 31;
        *(float4*)&Ws[k][c]      = *(const float4*)(Wm + i);
        *(float4*)&Ws[k][32 + c] = *(const float4*)(Wl + i);
    }
    __syncthreads();

    int lane = t & 63;
    float bj = (lane < 32) ? bm[lane] : bl[lane - 32];

    int gw = (blockIdx.x * blockDim.x + t) >> 6;
    int TW = (gridDim.x * blockDim.x) >> 6;
    for (int i = gw; i < N; i += TW) {
        float4 r = agg_node_h(Hin, row_ptr, col, dinv[i], i, lane);
        float a[4] = {r.x, r.y, r.z, r.w};
        // out[j] = sum_k g[k]*Ws[k][j] + b[j]; g[k] lives in lane (k>>2), comp (k&3).
        // 4 independent accumulators break the 64-deep serial FMA chain.
        float o0 = bj, o1 = 0.f, o2 = 0.f, o3 = 0.f;
#pragma unroll
        for (int k = 0; k < 64; k += 4) {
            int src = k >> 2;
            o0 = fmaf(__shfl(a[0], src, 64), Ws[k + 0][lane], o0);
            o1 = fmaf(__shfl(a[1], src, 64), Ws[k + 1][lane], o1);
            o2 = fmaf(__shfl(a[2], src, 64), Ws[k + 2][lane], o2);
            o3 = fmaf(__shfl(a[3], src, 64), Ws[k + 3][lane], o3);
        }
        float o = (o0 + o1) + (o2 + o3);
        if (lane < 32) out[(size_t)i * 32 + lane] = o;
        else           out[(size_t)(N + i) * 32 + (lane - 32)] = o;
    }
}

// ---------------- launch ----------------

extern "C" void kernel_launch(void* const* d_in, const int* in_sizes, int n_in,
                              void* d_out, int out_size, void* d_ws, size_t ws_size,
                              hipStream_t stream) {
    const float* x  = (const float*)d_in[0];
    const int*   ei = (const int*)d_in[1];   // int32 (JAX default int)
    const float* W0 = (const float*)d_in[2];
    const float* b0 = (const float*)d_in[3];
    const float* Wm = (const float*)d_in[4];
    const float* bm = (const float*)d_in[5];
    const float* Wl = (const float*)d_in[6];
    const float* bl = (const float*)d_in[7];
    float* out = (float*)d_out;

    int N = in_sizes[0] / 128;
    int E = in_sizes[1] / 2;
    const int* src = ei;
    const int* dst = ei + E;

    char* p = (char*)d_ws;
    auto carve = [&](size_t bytes) -> void* {
        void* q = (void*)p;
        p += (bytes + 255) & ~(size_t)255;
        return q;
    };
    int*    count    = (int*)carve((size_t)N * 4);
    int*    row_ptr  = (int*)carve(((size_t)N + 1) * 4);
    int*    col      = (int*)carve((size_t)E * 4);
    int*    rank     = (int*)carve((size_t)E * 4);
    float*  dinv     = (float*)carve((size_t)N * 4);
    int*    partials = (int*)carve(128 * 4);
    __half* h0       = (__half*)carve((size_t)N * 64 * 2);  // dinv*(x@W0) (fp16)
    __half* h        = (__half*)carve((size_t)N * 64 * 2);  // dinv*relu'd hidden (fp16)

    int nb = (N + 1023) / 1024;  // scan blocks (<=128 for N<=131072)

    hipMemsetAsync(count, 0, (size_t)N * 4, stream);
    hist_rank_kernel<<<2048, 256, 0, stream>>>(dst, E, count, rank);
    scan_partial_kernel<<<nb, 256, 0, stream>>>(count, partials, N);
    scan_top_kernel<<<1, 128, 0, stream>>>(partials, nb, row_ptr, N);
    scan_apply_kernel<<<nb, 256, 0, stream>>>(count, partials, row_ptr, dinv, N);
    scatter_kernel<<<2048, 256, 0, stream>>>(src, dst, rank, E, row_ptr, col, N);

    // layer 0: h0' = dinv * (x @ W0) ; h' = dinv * relu(agg(h0') + b0)
    gemm_kernel<<<(N + 63) / 64, 256, 0, stream>>>(x, W0, dinv, h0, N);
    agg_relu_kernel<<<(N + 3) / 4, 256, 0, stream>>>(h0, row_ptr, col, dinv, b0, h, N);

    // layer 2 fused: out = [agg(h')@Wm + bm | agg(h')@Wl + bl]
    agg_out_fused_kernel<<<2048, 256, 0, stream>>>(h, row_ptr, col, dinv, Wm, Wl, bm, bl, out, N);
}

// Round 10
// 274.070 us; speedup vs baseline: 1.2636x; 1.2636x over previous
//
#include <hip/hip_runtime.h>
#include <hip/hip_fp16.h>

// ---------------- preprocessing: histogram+rank, 3-phase scan (+dinv), passed scatter ----

__global__ void hist_rank_kernel(const int* __restrict__ dst, int E, int* __restrict__ count,
                                 int* __restrict__ rank) {
    int stride = gridDim.x * blockDim.x;
    int t = blockIdx.x * blockDim.x + threadIdx.x;
    int E4 = E >> 2;
    for (int e = t; e < E4; e += stride) {
        int4 d = ((const int4*)dst)[e];
        int4 r;
        r.x = atomicAdd(&count[d.x], 1);
        r.y = atomicAdd(&count[d.y], 1);
        r.z = atomicAdd(&count[d.z], 1);
        r.w = atomicAdd(&count[d.w], 1);
        ((int4*)rank)[e] = r;
    }
    for (int e = (E4 << 2) + t; e < E; e += stride) rank[e] = atomicAdd(&count[dst[e]], 1);
}

__global__ void scan_partial_kernel(const int* __restrict__ count, int* __restrict__ partials,
                                    int N) {
    __shared__ int red[4];
    int t = threadIdx.x;
    int idx = blockIdx.x * 1024 + t * 4;
    int s = 0;
    if (idx + 3 < N) {
        int4 c = *(const int4*)(count + idx);
        s = c.x + c.y + c.z + c.w;
    } else {
#pragma unroll
        for (int k = 0; k < 4; ++k)
            if (idx + k < N) s += count[idx + k];
    }
#pragma unroll
    for (int off = 1; off < 64; off <<= 1) s += __shfl_xor(s, off);
    if ((t & 63) == 0) red[t >> 6] = s;
    __syncthreads();
    if (t == 0) partials[blockIdx.x] = red[0] + red[1] + red[2] + red[3];
}

__global__ void scan_top_kernel(int* __restrict__ partials, int nb, int* __restrict__ row_ptr,
                                int N) {
    __shared__ int buf[2][128];
    int t = threadIdx.x;
    buf[0][t] = (t < nb) ? partials[t] : 0;
    __syncthreads();
    int pi = 0;
    for (int off = 1; off < 128; off <<= 1) {
        int v = buf[pi][t];
        if (t >= off) v += buf[pi][t - off];
        buf[pi ^ 1][t] = v;
        pi ^= 1;
        __syncthreads();
    }
    if (t < nb) partials[t] = (t == 0) ? 0 : buf[pi][t - 1];
    if (t == 0) row_ptr[N] = buf[pi][127];
}

__global__ void scan_apply_kernel(const int* __restrict__ count, const int* __restrict__ partials,
                                  int* __restrict__ row_ptr, float* __restrict__ dinv, int N) {
    __shared__ int wsum[4];
    int t = threadIdx.x;
    int idx = blockIdx.x * 1024 + t * 4;
    int4 c = make_int4(0, 0, 0, 0);
    if (idx + 3 < N) {
        c = *(const int4*)(count + idx);
    } else {
        if (idx + 0 < N) c.x = count[idx + 0];
        if (idx + 1 < N) c.y = count[idx + 1];
        if (idx + 2 < N) c.z = count[idx + 2];
    }
    int s = c.x + c.y + c.z + c.w;
    int incl = s;
#pragma unroll
    for (int off = 1; off < 64; off <<= 1) {
        int v = __shfl_up(incl, off);
        if ((t & 63) >= off) incl += v;
    }
    int wexcl = incl - s;
    int w = t >> 6;
    if ((t & 63) == 63) wsum[w] = incl;
    __syncthreads();
    int base = partials[blockIdx.x] + wexcl;
    for (int k = 0; k < w; ++k) base += wsum[k];
    if (idx + 0 < N) { row_ptr[idx + 0] = base;                   dinv[idx + 0] = rsqrtf((float)c.x + 1.f); }
    if (idx + 1 < N) { row_ptr[idx + 1] = base + c.x;             dinv[idx + 1] = rsqrtf((float)c.y + 1.f); }
    if (idx + 2 < N) { row_ptr[idx + 2] = base + c.x + c.y;       dinv[idx + 2] = rsqrtf((float)c.z + 1.f); }
    if (idx + 3 < N) { row_ptr[idx + 3] = base + c.x + c.y + c.z; dinv[idx + 3] = rsqrtf((float)c.w + 1.f); }
}

// atomic-free scatter with dst-range write blocking (pass p writes only a ~N/NPASS window)
#define NPASS 8
__global__ void scatter_kernel(const int* __restrict__ src, const int* __restrict__ dst,
                               const int* __restrict__ rank, int E,
                               const int* __restrict__ row_ptr, int* __restrict__ col, int N) {
    int chunk = (N + NPASS - 1) / NPASS;
    int stride = gridDim.x * blockDim.x;
    int t = blockIdx.x * blockDim.x + threadIdx.x;
    int E4 = E >> 2;
    for (int pass = 0; pass < NPASS; ++pass) {
        int lo = pass * chunk, hi = min(lo + chunk, N);
        for (int e = t; e < E4; e += stride) {
            int4 d = ((const int4*)dst)[e];
            int4 s = ((const int4*)src)[e];
            int4 r = ((const int4*)rank)[e];
            if (d.x >= lo && d.x < hi) col[row_ptr[d.x] + r.x] = s.x;
            if (d.y >= lo && d.y < hi) col[row_ptr[d.y] + r.y] = s.y;
            if (d.z >= lo && d.z < hi) col[row_ptr[d.z] + r.z] = s.z;
            if (d.w >= lo && d.w < hi) col[row_ptr[d.w] + r.w] = s.w;
        }
        for (int e = (E4 << 2) + t; e < E; e += stride) {
            int d = dst[e];
            if (d >= lo && d < hi) col[row_ptr[d] + rank[e]] = src[e];
        }
    }
}

// -------- fp32 GEMM, PRE-SCALED fp16 output: Out[r] = dinv[r] * (A @ W)[r] --------------

__global__ __launch_bounds__(256, 2) void gemm_kernel(const float* __restrict__ A,
                                                      const float* __restrict__ W,
                                                      const float* __restrict__ dinv,
                                                      __half* __restrict__ Out, int M) {
    const int K = 128;
    __shared__ float Ws[K][64];
    __shared__ float As[64][68];
    int t = threadIdx.x;
    for (int i = t * 4; i < K * 64; i += 1024)
        *(float4*)&Ws[i >> 6][i & 63] = *(const float4*)(W + i);

    int row0 = blockIdx.x * 64;
    int rt = (t >> 4) * 4;
    int ct = (t & 15) * 4;
    float acc[4][4];
#pragma unroll
    for (int m = 0; m < 4; m++) { acc[m][0] = 0.f; acc[m][1] = 0.f; acc[m][2] = 0.f; acc[m][3] = 0.f; }

    for (int k0 = 0; k0 < K; k0 += 64) {
        __syncthreads();
        for (int i = t * 4; i < 64 * 64; i += 1024) {
            int r = i >> 6, c = i & 63;
            int gr = row0 + r;
            float4 v = make_float4(0.f, 0.f, 0.f, 0.f);
            if (gr < M) v = *(const float4*)(A + (size_t)gr * K + k0 + c);
            *(float4*)&As[r][c] = v;
        }
        __syncthreads();
#pragma unroll
        for (int kk = 0; kk < 64; ++kk) {
            float a0 = As[rt + 0][kk], a1 = As[rt + 1][kk];
            float a2 = As[rt + 2][kk], a3 = As[rt + 3][kk];
            float4 w = *(float4*)&Ws[k0 + kk][ct];
            acc[0][0] += a0 * w.x; acc[0][1] += a0 * w.y; acc[0][2] += a0 * w.z; acc[0][3] += a0 * w.w;
            acc[1][0] += a1 * w.x; acc[1][1] += a1 * w.y; acc[1][2] += a1 * w.z; acc[1][3] += a1 * w.w;
            acc[2][0] += a2 * w.x; acc[2][1] += a2 * w.y; acc[2][2] += a2 * w.z; acc[2][3] += a2 * w.w;
            acc[3][0] += a3 * w.x; acc[3][1] += a3 * w.y; acc[3][2] += a3 * w.z; acc[3][3] += a3 * w.w;
        }
    }
#pragma unroll
    for (int m = 0; m < 4; m++) {
        int gr = row0 + rt + m;
        if (gr < M) {
            float dv = dinv[gr];
            union { uint2 u; __half h[4]; } pk;
            pk.h[0] = __float2half(dv * acc[m][0]);
            pk.h[1] = __float2half(dv * acc[m][1]);
            pk.h[2] = __float2half(dv * acc[m][2]);
            pk.h[3] = __float2half(dv * acc[m][3]);
            *(uint2*)(Out + (size_t)gr * 64 + ct) = pk.u;
        }
    }
}

// -------- pipelined edge-aggregation core (pre-scaled fp16 payload) ---------------------
// Grid-stride over nodes. Round A (first 16 edges, predicated) uses col indices
// PREFETCHED during the previous iteration, so the rowptr->col latency of node i+TW
// hides under node i's row loads + epilogue. deg>16 falls back to dynamic 16-edge
// rounds (R8 structure: 4 col + 4 row loads per group, compiler overlaps rounds).
// wave = 4 groups x 16 lanes; lane l covers channels 4(l&15)..+3.

// accumulate rounds for edges [beg..end) given prefetched first-round cols pc[4]
__device__ __forceinline__ float4 agg_body(const __half* __restrict__ Hin,
                                           const int* __restrict__ col,
                                           const int* pc, int beg, int end,
                                           int i, int g, int l) {
    float4 acc = make_float4(0.f, 0.f, 0.f, 0.f);
    if (g == 0) {  // self-loop (pre-scaled: h'_i)
        union { uint2 u; __half h[4]; } v;
        v.u = *(const uint2*)(Hin + (size_t)i * 64 + l * 4);
        acc.x = __half2float(v.h[0]); acc.y = __half2float(v.h[1]);
        acc.z = __half2float(v.h[2]); acc.w = __half2float(v.h[3]);
    }
    {   // round A: prefetched cols, predicated by weight
        float w[4];
        uint2 vv[4];
#pragma unroll
        for (int k = 0; k < 4; ++k) {
            w[k] = (beg + g + 4 * k < end) ? 1.f : 0.f;
            vv[k] = *(const uint2*)(Hin + (size_t)pc[k] * 64 + l * 4);
        }
#pragma unroll
        for (int k = 0; k < 4; ++k) {
            union { uint2 u; __half h[4]; } v;
            v.u = vv[k];
            acc.x = fmaf(w[k], __half2float(v.h[0]), acc.x);
            acc.y = fmaf(w[k], __half2float(v.h[1]), acc.y);
            acc.z = fmaf(w[k], __half2float(v.h[2]), acc.z);
            acc.w = fmaf(w[k], __half2float(v.h[3]), acc.w);
        }
    }
    // overflow (deg>16): dynamic rounds
    int e = beg + 16;
    for (; e + 16 <= end; e += 16) {  // full rounds, unpredicated
        int s[4];
#pragma unroll
        for (int k = 0; k < 4; ++k) s[k] = col[e + g + 4 * k];
        uint2 vv[4];
#pragma unroll
        for (int k = 0; k < 4; ++k) vv[k] = *(const uint2*)(Hin + (size_t)s[k] * 64 + l * 4);
#pragma unroll
        for (int k = 0; k < 4; ++k) {
            union { uint2 u; __half h[4]; } v;
            v.u = vv[k];
            acc.x += __half2float(v.h[0]); acc.y += __half2float(v.h[1]);
            acc.z += __half2float(v.h[2]); acc.w += __half2float(v.h[3]);
        }
    }
    if (e < end) {  // predicated tail
        float w[4];
        uint2 vv[4];
#pragma unroll
        for (int k = 0; k < 4; ++k) {
            int ie = e + g + 4 * k;
            int s = (ie < end) ? col[ie] : 0;
            w[k] = (ie < end) ? 1.f : 0.f;
            vv[k] = *(const uint2*)(Hin + (size_t)s * 64 + l * 4);
        }
#pragma unroll
        for (int k = 0; k < 4; ++k) {
            union { uint2 u; __half h[4]; } v;
            v.u = vv[k];
            acc.x = fmaf(w[k], __half2float(v.h[0]), acc.x);
            acc.y = fmaf(w[k], __half2float(v.h[1]), acc.y);
            acc.z = fmaf(w[k], __half2float(v.h[2]), acc.z);
            acc.w = fmaf(w[k], __half2float(v.h[3]), acc.w);
        }
    }
    acc.x += __shfl_xor(acc.x, 16); acc.y += __shfl_xor(acc.y, 16);
    acc.z += __shfl_xor(acc.z, 16); acc.w += __shfl_xor(acc.w, 16);
    acc.x += __shfl_xor(acc.x, 32); acc.y += __shfl_xor(acc.y, 32);
    acc.z += __shfl_xor(acc.z, 32); acc.w += __shfl_xor(acc.w, 32);
    return acc;
}

// layer 1: t = relu(agg + b0); store pre-scaled h' = dinv_i * t   (fp16)
__global__ __launch_bounds__(256, 4) void agg_relu_kernel(
        const __half* __restrict__ Hin, const int* __restrict__ row_ptr,
        const int* __restrict__ col, const float* __restrict__ dinv,
        const float* __restrict__ bias, __half* __restrict__ Hout, int N) {
    int t = threadIdx.x;
    int lane = t & 63;
    int g = lane >> 4, l = lane & 15;
    int gw = (blockIdx.x * blockDim.x + t) >> 6;
    int TW = (gridDim.x * blockDim.x) >> 6;

    float4 b4 = (l < 16) ? *(const float4*)(bias + l * 4) : make_float4(0, 0, 0, 0);

    int i = gw;
    int beg = 0, end = 0, pc0 = 0, pc1 = 0, pc2 = 0, pc3 = 0;
    if (i < N) {
        beg = row_ptr[i]; end = row_ptr[i + 1];
        pc0 = (beg + g      < end) ? col[beg + g]      : 0;
        pc1 = (beg + g + 4  < end) ? col[beg + g + 4]  : 0;
        pc2 = (beg + g + 8  < end) ? col[beg + g + 8]  : 0;
        pc3 = (beg + g + 12 < end) ? col[beg + g + 12] : 0;
    }
    while (i < N) {
        int inext = i + TW;
        int beg_n = 0, end_n = 0;
        if (inext < N) { beg_n = row_ptr[inext]; end_n = row_ptr[inext + 1]; }

        int pc[4] = {pc0, pc1, pc2, pc3};
        float di = dinv[i];
        float4 r = agg_body(Hin, col, pc, beg, end, i, g, l);

        // prefetch next node's round-A cols (overlaps with this node's epilogue/store)
        if (inext < N) {
            pc0 = (beg_n + g      < end_n) ? col[beg_n + g]      : 0;
            pc1 = (beg_n + g + 4  < end_n) ? col[beg_n + g + 4]  : 0;
            pc2 = (beg_n + g + 8  < end_n) ? col[beg_n + g + 8]  : 0;
            pc3 = (beg_n + g + 12 < end_n) ? col[beg_n + g + 12] : 0;
        }

        if (lane < 16) {
            float s = di * di;  // r holds raw sum; result = di*(sum) ; store dinv*(relu(...))
            union { uint2 u; __half h[4]; } pk;
            pk.h[0] = __float2half(di * fmaxf(di * r.x + b4.x, 0.f));
            pk.h[1] = __float2half(di * fmaxf(di * r.y + b4.y, 0.f));
            pk.h[2] = __float2half(di * fmaxf(di * r.z + b4.z, 0.f));
            pk.h[3] = __float2half(di * fmaxf(di * r.w + b4.w, 0.f));
            (void)s;
            *(uint2*)(Hout + (size_t)i * 64 + l * 4) = pk.u;
        }
        beg = beg_n; end = end_n; i = inext;
    }
}

// layer 2 FUSED: g = agg(h); out = [ g@Wm + bm | g@Wl + bl ]  (agg(h@W) == agg(h)@W)
__global__ __launch_bounds__(256, 4) void agg_out_fused_kernel(
        const __half* __restrict__ Hin, const int* __restrict__ row_ptr,
        const int* __restrict__ col, const float* __restrict__ dinv,
        const float* __restrict__ Wm, const float* __restrict__ Wl,
        const float* __restrict__ bm, const float* __restrict__ bl,
        float* __restrict__ out, int N) {
    __shared__ float Ws[64][64];
    int t = threadIdx.x;
    for (int i = t * 4; i < 64 * 32; i += 1024) {
        int k = i >> 5, c = i & 31;
        *(float4*)&Ws[k][c]      = *(const float4*)(Wm + i);
        *(float4*)&Ws[k][32 + c] = *(const float4*)(Wl + i);
    }
    __syncthreads();

    int lane = t & 63;
    int g = lane >> 4, l = lane & 15;
    float bj = (lane < 32) ? bm[lane] : bl[lane - 32];

    int gw = (blockIdx.x * blockDim.x + t) >> 6;
    int TW = (gridDim.x * blockDim.x) >> 6;

    int i = gw;
    int beg = 0, end = 0, pc0 = 0, pc1 = 0, pc2 = 0, pc3 = 0;
    if (i < N) {
        beg = row_ptr[i]; end = row_ptr[i + 1];
        pc0 = (beg + g      < end) ? col[beg + g]      : 0;
        pc1 = (beg + g + 4  < end) ? col[beg + g + 4]  : 0;
        pc2 = (beg + g + 8  < end) ? col[beg + g + 8]  : 0;
        pc3 = (beg + g + 12 < end) ? col[beg + g + 12] : 0;
    }
    while (i < N) {
        int inext = i + TW;
        int beg_n = 0, end_n = 0;
        if (inext < N) { beg_n = row_ptr[inext]; end_n = row_ptr[inext + 1]; }

        int pc[4] = {pc0, pc1, pc2, pc3};
        float di = dinv[i];
        float4 r = agg_body(Hin, col, pc, beg, end, i, g, l);

        // prefetch next node's round-A cols (overlaps with MLP epilogue below)
        if (inext < N) {
            pc0 = (beg_n + g      < end_n) ? col[beg_n + g]      : 0;
            pc1 = (beg_n + g + 4  < end_n) ? col[beg_n + g + 4]  : 0;
            pc2 = (beg_n + g + 8  < end_n) ? col[beg_n + g + 8]  : 0;
            pc3 = (beg_n + g + 12 < end_n) ? col[beg_n + g + 12] : 0;
        }

        float a[4] = {di * r.x, di * r.y, di * r.z, di * r.w};
        // out[j] = sum_k gk*Ws[k][j] + b[j]; gk lives in lane (k>>2), comp (k&3).
        float o0 = bj, o1 = 0.f, o2 = 0.f, o3 = 0.f;
#pragma unroll
        for (int k = 0; k < 64; k += 4) {
            int srcl = k >> 2;
            o0 = fmaf(__shfl(a[0], srcl, 64), Ws[k + 0][lane], o0);
            o1 = fmaf(__shfl(a[1], srcl, 64), Ws[k + 1][lane], o1);
            o2 = fmaf(__shfl(a[2], srcl, 64), Ws[k + 2][lane], o2);
            o3 = fmaf(__shfl(a[3], srcl, 64), Ws[k + 3][lane], o3);
        }
        float o = (o0 + o1) + (o2 + o3);
        if (lane < 32) out[(size_t)i * 32 + lane] = o;
        else           out[(size_t)(N + i) * 32 + (lane - 32)] = o;

        beg = beg_n; end = end_n; i = inext;
    }
}

// ---------------- launch ----------------

extern "C" void kernel_launch(void* const* d_in, const int* in_sizes, int n_in,
                              void* d_out, int out_size, void* d_ws, size_t ws_size,
                              hipStream_t stream) {
    const float* x  = (const float*)d_in[0];
    const int*   ei = (const int*)d_in[1];   // int32 (JAX default int)
    const float* W0 = (const float*)d_in[2];
    const float* b0 = (const float*)d_in[3];
    const float* Wm = (const float*)d_in[4];
    const float* bm = (const float*)d_in[5];
    const float* Wl = (const float*)d_in[6];
    const float* bl = (const float*)d_in[7];
    float* out = (float*)d_out;

    int N = in_sizes[0] / 128;
    int E = in_sizes[1] / 2;
    const int* src = ei;
    const int* dst = ei + E;

    char* p = (char*)d_ws;
    auto carve = [&](size_t bytes) -> void* {
        void* q = (void*)p;
        p += (bytes + 255) & ~(size_t)255;
        return q;
    };
    int*    count    = (int*)carve((size_t)N * 4);
    int*    row_ptr  = (int*)carve(((size_t)N + 1) * 4);
    int*    col      = (int*)carve((size_t)E * 4);
    int*    rank     = (int*)carve((size_t)E * 4);
    float*  dinv     = (float*)carve((size_t)N * 4);
    int*    partials = (int*)carve(128 * 4);
    __half* h0       = (__half*)carve((size_t)N * 64 * 2);  // dinv*(x@W0) (fp16)
    __half* h        = (__half*)carve((size_t)N * 64 * 2);  // dinv*relu'd hidden (fp16)

    int nb = (N + 1023) / 1024;  // scan blocks (<=128 for N<=131072)

    hipMemsetAsync(count, 0, (size_t)N * 4, stream);
    hist_rank_kernel<<<2048, 256, 0, stream>>>(dst, E, count, rank);
    scan_partial_kernel<<<nb, 256, 0, stream>>>(count, partials, N);
    scan_top_kernel<<<1, 128, 0, stream>>>(partials, nb, row_ptr, N);
    scan_apply_kernel<<<nb, 256, 0, stream>>>(count, partials, row_ptr, dinv, N);
    scatter_kernel<<<2048, 256, 0, stream>>>(src, dst, rank, E, row_ptr, col, N);

    // layer 0: h0' = dinv * (x @ W0) ; h' = dinv * relu(agg(h0') + b0)
    gemm_kernel<<<(N + 63) / 64, 256, 0, stream>>>(x, W0, dinv, h0, N);
    agg_relu_kernel<<<2048, 256, 0, stream>>>(h0, row_ptr, col, dinv, b0, h, N);

    // layer 2 fused: out = [agg(h')@Wm + bm | agg(h')@Wl + bl]
    agg_out_fused_kernel<<<2048, 256, 0, stream>>>(h, row_ptr, col, dinv, Wm, Wl, bm, bl, out, N);
}